// Round 9
// baseline (697.798 us; speedup 1.0000x reference)
//
#include <hip/hip_runtime.h>
#include <hip/hip_bf16.h>

// DCSA block, round 9: 128x64 tile, BK=64, 16 MFMA per barrier-pair in the
// shared mgemm/mconv skeleton (was 64x64/BK=32, 4 MFMA -> barrier-bound,
// MfmaUtil 11%). Attention/LN/dwgelu unchanged from round 8 (verified).

using bf16 = __hip_bfloat16;
typedef short v8s __attribute__((ext_vector_type(8)));
typedef float v4f  __attribute__((ext_vector_type(4)));

static __device__ __forceinline__ float bf2f(bf16 x) { return __bfloat162float(x); }
static __device__ __forceinline__ float us2f(unsigned short u)
{ union { unsigned int i; float f; } x; x.i = ((unsigned)u) << 16; return x.f; }
static __device__ __forceinline__ unsigned short f2us(float f)
{ bf16 h = __float2bfloat16(f); return *(unsigned short*)&h; }
static __device__ __forceinline__ float ldi(const void* p, size_t i, int isbf)
{ return isbf ? bf2f(((const bf16*)p)[i]) : ((const float*)p)[i]; }

// ---------------------------------------------------------------------------
__global__ void detect_kernel(const unsigned short* p, int* flag)
{
    if (threadIdx.x == 0 && blockIdx.x == 0)
        *flag = (p[0] == 0x3F80) ? 1 : 0;
}

// ---------------------------------------------------------------------------
struct CvtArgs { const void* src[20]; unsigned off[21]; };

__global__ __launch_bounds__(256) void cvt_lin(CvtArgs a, const int* __restrict__ flag,
                                               bf16* __restrict__ dst)
{
    unsigned e = blockIdx.x * 256u + threadIdx.x;
    int isbf = *flag;
    int s = 0;
    while (e >= a.off[s + 1]) ++s;
    dst[e] = __float2bfloat16(ldi(a.src[s], e - a.off[s], isbf));
}

// ---------------------------------------------------------------------------
// CHW [b][256][1024] (raw dtype) -> NHWC [b*1024][256] bf16.
// ---------------------------------------------------------------------------
__global__ __launch_bounds__(256) void tcvt(const void* __restrict__ src,
                                            const int* __restrict__ flag,
                                            bf16* __restrict__ dst)
{
    __shared__ float T[64][65];
    int hw0 = blockIdx.x * 64, c0 = blockIdx.y * 64, b = blockIdx.z;
    int t = threadIdx.x, isbf = *flag;
    int c = t >> 2, x16 = (t & 3) * 16;
    size_t sbase = ((size_t)b * 256 + c0 + c) * 1024 + hw0 + x16;
#pragma unroll
    for (int j = 0; j < 16; ++j) T[c][x16 + j] = ldi(src, sbase + j, isbf);
    __syncthreads();
    int hw = t >> 2, c16 = (t & 3) * 16;
    bf16* dp = dst + ((size_t)(b << 10) + hw0 + hw) * 256 + c0 + c16;
#pragma unroll
    for (int j = 0; j < 16; ++j) dp[j] = __float2bfloat16(T[c16 + j][hw]);
}

// ---------------------------------------------------------------------------
template <int KS>
__global__ __launch_bounds__(256) void repack_conv(const void* __restrict__ W,
                                                   const int* __restrict__ flag,
                                                   bf16* __restrict__ Wr)
{
    int idx = blockIdx.x * 256 + threadIdx.x;
    int isbf = *flag;
    int ci = idx & 255, o = (idx >> 8) & 255, khkw = idx >> 16;
    int kh = khkw / KS, kw = khkw % KS;
    Wr[idx] = __float2bfloat16(
        ldi(W, (((size_t)o * 256 + ci) * KS + kh) * KS + kw, isbf));
}

__global__ __launch_bounds__(256) void repack_dw(const void* __restrict__ W,
                                                 const int* __restrict__ flag,
                                                 bf16* __restrict__ Wr)
{
    int idx = blockIdx.x * 256 + threadIdx.x;
    int isbf = *flag;
    int c = idx & 1023, tap = idx >> 10;
    Wr[idx] = __float2bfloat16(ldi(W, (size_t)c * 9 + tap, isbf));
}

// ---------------------------------------------------------------------------
// MFMA GEMM, 128(m) x 64(n) tile, BK=64, 4 waves (each 32m x 64n, 16 MFMA
// per barrier-pair). MA:[M][K], MB:[N][K] k-contig.
// modes:
//  0: m=pixel, n=o  -> Yb NHWC [m*Ochan+n] (+R)
//  1: m=o, n=pixel  -> Yb CHW [b][Ochan][1024]
//  2: m=o, n=pixel  -> Yf CHW fp32 + R NHWC[p*256+o]
//  3: m=o(768), n=p -> o<512: Yb(QK)[p*512+o]; o>=512: Y2(V) CHW 256ch
//  4: m=o(256), n=p -> Yb(QK)[p*512 + Ochan + o]
// ---------------------------------------------------------------------------
__global__ __launch_bounds__(256) void mgemm(
    const short* __restrict__ MA, const short* __restrict__ MB,
    bf16* __restrict__ Yb, float* __restrict__ Yf, bf16* __restrict__ Y2,
    const bf16* __restrict__ R, int K, int mode, int Ochan)
{
    __shared__ short As[128][72], Bs[64][72];
    int m0 = blockIdx.x * 128, n0 = blockIdx.y * 64;
    int t = threadIdx.x, lane = t & 63, wv = t >> 6;
    int l15 = lane & 15, quad = lane >> 4;
    int ar = t >> 1, ac = (t & 1) * 32;       // A staging: 128 rows x 64
    int br = t >> 2, bc = (t & 3) * 16;       // B staging: 64 rows x 64

    v4f acc[2][4] = {};

    for (int k0 = 0; k0 < K; k0 += 64) {
        const short* sa = &MA[(size_t)(m0 + ar) * K + k0 + ac];
#pragma unroll
        for (int j = 0; j < 4; ++j) *(v8s*)&As[ar][ac + j * 8] = *(const v8s*)&sa[j * 8];
        const short* sb = &MB[(size_t)(n0 + br) * K + k0 + bc];
        *(v8s*)&Bs[br][bc]     = *(const v8s*)&sb[0];
        *(v8s*)&Bs[br][bc + 8] = *(const v8s*)&sb[8];
        __syncthreads();
#pragma unroll
        for (int kk = 0; kk < 2; ++kk) {
            v8s a0 = *(const v8s*)&As[wv * 32 + l15][kk * 32 + quad * 8];
            v8s a1 = *(const v8s*)&As[wv * 32 + 16 + l15][kk * 32 + quad * 8];
#pragma unroll
            for (int nt = 0; nt < 4; ++nt) {
                v8s b = *(const v8s*)&Bs[nt * 16 + l15][kk * 32 + quad * 8];
                acc[0][nt] = __builtin_amdgcn_mfma_f32_16x16x32_bf16(a0, b, acc[0][nt], 0, 0, 0);
                acc[1][nt] = __builtin_amdgcn_mfma_f32_16x16x32_bf16(a1, b, acc[1][nt], 0, 0, 0);
            }
        }
        __syncthreads();
    }

#pragma unroll
    for (int mt = 0; mt < 2; ++mt)
#pragma unroll
        for (int nt = 0; nt < 4; ++nt)
#pragma unroll
            for (int r = 0; r < 4; ++r) {
                int mm = m0 + wv * 32 + mt * 16 + quad * 4 + r;
                int nn = n0 + nt * 16 + l15;
                float v = acc[mt][nt][r];
                if (mode == 0) {
                    size_t off = (size_t)mm * Ochan + nn;
                    if (R) v += bf2f(R[off]);
                    Yb[off] = __float2bfloat16(v);
                } else if (mode == 1) {
                    Yb[((size_t)(nn >> 10) * Ochan + mm) * 1024 + (nn & 1023)] =
                        __float2bfloat16(v);
                } else if (mode == 2) {
                    Yf[((size_t)(nn >> 10) * Ochan + mm) * 1024 + (nn & 1023)] =
                        v + bf2f(R[(size_t)nn * 256 + mm]);
                } else if (mode == 3) {
                    if (mm < 512) Yb[(size_t)nn * 512 + mm] = __float2bfloat16(v);
                    else Y2[((size_t)(nn >> 10) * 256 + (mm - 512)) * 1024 + (nn & 1023)] =
                             __float2bfloat16(v);
                } else {
                    Yb[(size_t)nn * 512 + Ochan + mm] = __float2bfloat16(v);
                }
            }
}

// ---------------------------------------------------------------------------
// MFMA conv, same 128(pixels) x 64(o) / BK=64 skeleton, im2col A staging.
// grid (64, 4).
// ---------------------------------------------------------------------------
template <int KS, int PAD>
__global__ __launch_bounds__(256) void mconv(
    const short* __restrict__ Xn, const short* __restrict__ Wr,
    bf16* __restrict__ Y)
{
    const int K = 256 * KS * KS;
    __shared__ short As[128][72], Bs[64][72];
    int p0 = blockIdx.x * 128, o0 = blockIdx.y * 64;
    int t = threadIdx.x, lane = t & 63, wv = t >> 6;
    int l15 = lane & 15, quad = lane >> 4;
    int ar = t >> 1, ac = (t & 1) * 32;
    int br = t >> 2, bc = (t & 3) * 16;

    int p  = p0 + ar;
    int hw = p & 1023, hh = hw >> 5, ww = hw & 31;
    size_t ib = ((size_t)(p >> 10)) << 10;

    v4f acc[2][4] = {};

    for (int k0 = 0; k0 < K; k0 += 64) {
        int khkw = k0 >> 8;
        int kh = khkw / KS, kw = khkw % KS;
        int hi = hh + kh - PAD, wi = ww + kw - PAD;
        int aci = (k0 & 255) + ac;
        if ((unsigned)hi < 32u && (unsigned)wi < 32u) {
            const short* sa = &Xn[(ib + (hi << 5) + wi) * 256 + aci];
#pragma unroll
            for (int j = 0; j < 4; ++j)
                *(v8s*)&As[ar][ac + j * 8] = *(const v8s*)&sa[j * 8];
        } else {
            v8s z = {0, 0, 0, 0, 0, 0, 0, 0};
#pragma unroll
            for (int j = 0; j < 4; ++j) *(v8s*)&As[ar][ac + j * 8] = z;
        }
        const short* sb = &Wr[((size_t)khkw * 256 + o0 + br) * 256 + (k0 & 255) + bc];
        *(v8s*)&Bs[br][bc]     = *(const v8s*)&sb[0];
        *(v8s*)&Bs[br][bc + 8] = *(const v8s*)&sb[8];
        __syncthreads();
#pragma unroll
        for (int kk = 0; kk < 2; ++kk) {
            v8s a0 = *(const v8s*)&As[wv * 32 + l15][kk * 32 + quad * 8];
            v8s a1 = *(const v8s*)&As[wv * 32 + 16 + l15][kk * 32 + quad * 8];
#pragma unroll
            for (int nt = 0; nt < 4; ++nt) {
                v8s b = *(const v8s*)&Bs[nt * 16 + l15][kk * 32 + quad * 8];
                acc[0][nt] = __builtin_amdgcn_mfma_f32_16x16x32_bf16(a0, b, acc[0][nt], 0, 0, 0);
                acc[1][nt] = __builtin_amdgcn_mfma_f32_16x16x32_bf16(a1, b, acc[1][nt], 0, 0, 0);
            }
        }
        __syncthreads();
    }

#pragma unroll
    for (int mt = 0; mt < 2; ++mt)
#pragma unroll
        for (int nt = 0; nt < 4; ++nt)
#pragma unroll
            for (int r = 0; r < 4; ++r) {
                int pp = p0 + wv * 32 + mt * 16 + quad * 4 + r;
                int oo = o0 + nt * 16 + l15;
                Y[(size_t)pp * 256 + oo] = __float2bfloat16(acc[mt][nt][r]);
            }
}

// ---------------------------------------------------------------------------
// MFMA flash attention (unchanged from round 8, verified).
// ---------------------------------------------------------------------------
__global__ __launch_bounds__(256) void attn_mfma(
    const bf16* __restrict__ QK, const bf16* __restrict__ V,
    bf16* __restrict__ Out)
{
    int b = blockIdx.z, h = blockIdx.y, n0 = blockIdx.x * 64;
    int t = threadIdx.x, lane = t & 63, wv = t >> 6;
    int l15 = lane & 15, quad = lane >> 4;

    __shared__ short Ps[4][16][72];

    const short* qk = (const short*)QK;
    const short* vp = (const short*)V + ((size_t)b * 256 + h * 64) * 1024;

    size_t qrow = ((size_t)b * 1024 + n0 + wv * 16 + l15) * 512 + h * 64;
    v8s qf0 = *(const v8s*)&qk[qrow + quad * 8];
    v8s qf1 = *(const v8s*)&qk[qrow + 32 + quad * 8];

    v4f oacc[4] = {};
    float mi[4], li[4];
#pragma unroll
    for (int r = 0; r < 4; ++r) { mi[r] = -1e30f; li[r] = 0.f; }
    const float LOG2E = 1.4426950408889634f;

    for (int m0 = 0; m0 < 1024; m0 += 64) {
        v4f sacc[4];
#pragma unroll
        for (int ct = 0; ct < 4; ++ct) {
            size_t krow = ((size_t)b * 1024 + m0 + ct * 16 + l15) * 512 + 256 + h * 64;
            v8s kf0 = *(const v8s*)&qk[krow + quad * 8];
            v8s kf1 = *(const v8s*)&qk[krow + 32 + quad * 8];
            v4f z = {0.f, 0.f, 0.f, 0.f};
            z = __builtin_amdgcn_mfma_f32_16x16x32_bf16(qf0, kf0, z, 0, 0, 0);
            z = __builtin_amdgcn_mfma_f32_16x16x32_bf16(qf1, kf1, z, 0, 0, 0);
            sacc[ct] = z;
        }

        float rmax[4];
#pragma unroll
        for (int r = 0; r < 4; ++r)
            rmax[r] = 0.125f * fmaxf(fmaxf(sacc[0][r], sacc[1][r]),
                                     fmaxf(sacc[2][r], sacc[3][r]));
#pragma unroll
        for (int mk = 1; mk <= 8; mk <<= 1)
#pragma unroll
            for (int r = 0; r < 4; ++r)
                rmax[r] = fmaxf(rmax[r], __shfl_xor(rmax[r], mk));

        float al[4];
#pragma unroll
        for (int r = 0; r < 4; ++r) {
            float mn = fmaxf(mi[r], rmax[r]);
            al[r] = exp2f((mi[r] - mn) * LOG2E);
            mi[r] = mn;
        }

        float psum[4] = {};
#pragma unroll
        for (int ct = 0; ct < 4; ++ct)
#pragma unroll
            for (int r = 0; r < 4; ++r) {
                float pvv = exp2f((sacc[ct][r] * 0.125f - mi[r]) * LOG2E);
                psum[r] += pvv;
                Ps[wv][quad * 4 + r][ct * 16 + l15] = (short)f2us(pvv);
            }
#pragma unroll
        for (int mk = 1; mk <= 8; mk <<= 1)
#pragma unroll
            for (int r = 0; r < 4; ++r)
                psum[r] += __shfl_xor(psum[r], mk);
#pragma unroll
        for (int r = 0; r < 4; ++r) {
            li[r] = li[r] * al[r] + psum[r];
#pragma unroll
            for (int dt = 0; dt < 4; ++dt) oacc[dt][r] *= al[r];
        }

        v8s pf0 = *(const v8s*)&Ps[wv][l15][quad * 8];
        v8s pf1 = *(const v8s*)&Ps[wv][l15][32 + quad * 8];
#pragma unroll
        for (int dt = 0; dt < 4; ++dt) {
            const short* vr = vp + (size_t)(dt * 16 + l15) * 1024 + m0;
            v8s vf0 = *(const v8s*)&vr[quad * 8];
            v8s vf1 = *(const v8s*)&vr[32 + quad * 8];
            oacc[dt] = __builtin_amdgcn_mfma_f32_16x16x32_bf16(pf0, vf0, oacc[dt], 0, 0, 0);
            oacc[dt] = __builtin_amdgcn_mfma_f32_16x16x32_bf16(pf1, vf1, oacc[dt], 0, 0, 0);
        }
    }

    float linv[4];
#pragma unroll
    for (int r = 0; r < 4; ++r) linv[r] = 1.0f / li[r];
    size_t pb = (size_t)b * 1024 + n0 + wv * 16;
#pragma unroll
    for (int dt = 0; dt < 4; ++dt)
#pragma unroll
        for (int r = 0; r < 4; ++r)
            Out[(pb + quad * 4 + r) * 256 + h * 64 + dt * 16 + l15] =
                __float2bfloat16(oacc[dt][r] * linv[r]);
}

// ---------------------------------------------------------------------------
__global__ __launch_bounds__(256) void ln_nhwc(
    const bf16* __restrict__ X, const bf16* __restrict__ g,
    const bf16* __restrict__ be, bf16* __restrict__ Y)
{
    int wv = threadIdx.x >> 6, lane = threadIdx.x & 63;
    size_t p = (size_t)blockIdx.x * 4 + wv;
    const ushort4 u = *(const ushort4*)(X + p * 256 + lane * 4);
    float v0 = us2f(u.x), v1 = us2f(u.y), v2 = us2f(u.z), v3 = us2f(u.w);
    float s = v0 + v1 + v2 + v3;
    float ss = v0 * v0 + v1 * v1 + v2 * v2 + v3 * v3;
#pragma unroll
    for (int off = 32; off; off >>= 1) {
        s  += __shfl_xor(s, off);
        ss += __shfl_xor(ss, off);
    }
    float mu   = s * (1.0f / 256.0f);
    float var  = ss * (1.0f / 256.0f) - mu * mu;
    float rstd = rsqrtf(fmaxf(var, 0.0f) + 1e-5f);
    const ushort4 gu = *(const ushort4*)((const unsigned short*)g + lane * 4);
    const ushort4 bu = *(const ushort4*)((const unsigned short*)be + lane * 4);
    ushort4 o;
    o.x = f2us((v0 - mu) * rstd * us2f(gu.x) + us2f(bu.x));
    o.y = f2us((v1 - mu) * rstd * us2f(gu.y) + us2f(bu.y));
    o.z = f2us((v2 - mu) * rstd * us2f(gu.z) + us2f(bu.z));
    o.w = f2us((v3 - mu) * rstd * us2f(gu.w) + us2f(bu.w));
    *(ushort4*)(Y + p * 256 + lane * 4) = o;
}

// ---------------------------------------------------------------------------
__global__ __launch_bounds__(256) void dwgelu_nhwc(
    const bf16* __restrict__ H, const bf16* __restrict__ Wr,
    bf16* __restrict__ Y)
{
    int idx = blockIdx.x * 256 + threadIdx.x;
    int p = idx >> 7, c8 = (idx & 127) * 8;
    int hw = p & 1023, hh = hw >> 5, ww = hw & 31;
    size_t ib = ((size_t)(p >> 10)) << 10;
    float acc[8] = {};
#pragma unroll
    for (int kh = 0; kh < 3; ++kh)
#pragma unroll
        for (int kw = 0; kw < 3; ++kw) {
            int hi = hh + kh - 1, wi = ww + kw - 1;
            if ((unsigned)hi < 32u && (unsigned)wi < 32u) {
                v8s hv = *(const v8s*)((const short*)H + (ib + (hi << 5) + wi) * 1024 + c8);
                v8s wvv = *(const v8s*)((const short*)Wr + (kh * 3 + kw) * 1024 + c8);
#pragma unroll
                for (int j = 0; j < 8; ++j)
                    acc[j] = fmaf(us2f((unsigned short)wvv[j]),
                                  us2f((unsigned short)hv[j]), acc[j]);
            }
        }
    short ov[8];
#pragma unroll
    for (int j = 0; j < 8; ++j) {
        float x = acc[j];
        ov[j] = (short)f2us(0.5f * x * (1.0f + erff(x * 0.70710678118654752f)));
    }
    v8s o = {ov[0], ov[1], ov[2], ov[3], ov[4], ov[5], ov[6], ov[7]};
    *(v8s*)((short*)Y + (size_t)p * 1024 + c8) = o;
}

// ---------------------------------------------------------------------------
extern "C" void kernel_launch(void* const* d_in, const int* in_sizes, int n_in,
                              void* d_out, int out_size, void* d_ws, size_t ws_size,
                              hipStream_t stream)
{
    static const int  lidx[20] = {4,5,6,7,8,9,10,11,12,13,14,15,16,17,18,19,20,21,22,24};
    static const unsigned lsz[20] = {256,256,256,256,256,256,256,256,256,256,
                                     196608,65536,196608,65536,
                                     65536,65536,65536,65536,262144,262144};
    CvtArgs args;
    unsigned pre[21]; pre[0] = 0;
    for (int i = 0; i < 20; ++i) {
        args.src[i] = d_in[lidx[i]];
        pre[i + 1] = pre[i] + lsz[i];
    }
    for (int i = 0; i < 21; ++i) args.off[i] = pre[i];
    const unsigned ltot = pre[20];

    int*  flag  = (int*)d_ws;
    bf16* canon = (bf16*)d_ws + 128;
    bf16* cn[25];
    for (int i = 0; i < 20; ++i) cn[lidx[i]] = canon + pre[i];

    bf16* Wr3  = canon + ltot;
    bf16* Wr5  = Wr3 + 589824;
    bf16* Wdwr = Wr5 + 1638400;
    const size_t SZ = 2097152;
    bf16* slab = Wdwr + 9216;
    bf16* qb   = slab + 0 * SZ;                    // q_branch -> x (NHWC)
    bf16* kvb  = slab + 1 * SZ;
    bf16* t0   = slab + 2 * SZ;
    bf16* q    = slab + 3 * SZ;
    bf16* kv   = slab + 4 * SZ;
    bf16* QKb  = slab + 5 * SZ;                    // 2 slots: [8192][512]
    bf16* Vb   = slab + 7 * SZ;                    // 1 slot: CHW
    bf16* hb   = slab + 5 * SZ;                    // 4 slots (QKb/Vb dead)
    bf16* h2   = slab + 1 * SZ;                    // 4 slots (kvb..kv dead)
    bf16* aopT = kvb;
    bf16* dopT = t0;
    float* out = (float*)d_out;

    dim3 blk(256);
    auto S = [](const bf16* p) { return (const short*)p; };

    detect_kernel<<<1, 64, 0, stream>>>((const unsigned short*)d_in[4], flag);
    cvt_lin<<<ltot / 256, blk, 0, stream>>>(args, flag, canon);
    tcvt<<<dim3(16, 4, 8), blk, 0, stream>>>(d_in[0], flag, aopT);
    tcvt<<<dim3(16, 4, 8), blk, 0, stream>>>(d_in[1], flag, dopT);
    repack_conv<3><<<2304, blk, 0, stream>>>(d_in[2], flag, Wr3);
    repack_conv<5><<<6400, blk, 0, stream>>>(d_in[3], flag, Wr5);
    repack_dw<<<36, blk, 0, stream>>>(d_in[23], flag, Wdwr);

    // branches
    mconv<3, 1><<<dim3(64, 4), blk, 0, stream>>>(S(aopT), (const short*)Wr3, qb);
    mconv<5, 2><<<dim3(64, 4), blk, 0, stream>>>(S(dopT), (const short*)Wr5, kvb);

    // q-branch self-attention
    ln_nhwc<<<2048, blk, 0, stream>>>(qb, cn[4], cn[5], t0);
    mgemm<<<dim3(6, 128), blk, 0, stream>>>(S(cn[14]), S(t0), QKb, nullptr, Vb, nullptr, 256, 3, 0);
    attn_mfma<<<dim3(16, 4, 8), blk, 0, stream>>>(QKb, Vb, t0);
    mgemm<<<dim3(64, 4), blk, 0, stream>>>(S(t0), S(cn[15]), qb, nullptr, nullptr, qb, 256, 0, 256);
    ln_nhwc<<<2048, blk, 0, stream>>>(qb, cn[8], cn[9], q);

    // kv-branch self-attention
    ln_nhwc<<<2048, blk, 0, stream>>>(kvb, cn[6], cn[7], t0);
    mgemm<<<dim3(6, 128), blk, 0, stream>>>(S(cn[16]), S(t0), QKb, nullptr, Vb, nullptr, 256, 3, 0);
    attn_mfma<<<dim3(16, 4, 8), blk, 0, stream>>>(QKb, Vb, t0);
    mgemm<<<dim3(64, 4), blk, 0, stream>>>(S(t0), S(cn[17]), kvb, nullptr, nullptr, kvb, 256, 0, 256);
    ln_nhwc<<<2048, blk, 0, stream>>>(kvb, cn[10], cn[11], kv);

    // cross attention
    mgemm<<<dim3(2, 128), blk, 0, stream>>>(S(cn[18]), S(q),  QKb, nullptr, nullptr, nullptr, 256, 4, 0);
    mgemm<<<dim3(2, 128), blk, 0, stream>>>(S(cn[19]), S(kv), QKb, nullptr, nullptr, nullptr, 256, 4, 256);
    mgemm<<<dim3(2, 128), blk, 0, stream>>>(S(cn[20]), S(kv), Vb,  nullptr, nullptr, nullptr, 256, 1, 256);
    attn_mfma<<<dim3(16, 4, 8), blk, 0, stream>>>(QKb, Vb, t0);
    mgemm<<<dim3(64, 4), blk, 0, stream>>>(S(t0), S(cn[21]), qb, nullptr, nullptr, qb, 256, 0, 256);

    // LeFF
    ln_nhwc<<<2048, blk, 0, stream>>>(qb, cn[12], cn[13], t0);
    mgemm<<<dim3(64, 16), blk, 0, stream>>>(S(t0), S(cn[22]), hb, nullptr, nullptr, nullptr, 256, 0, 1024);
    dwgelu_nhwc<<<4096, blk, 0, stream>>>(hb, Wdwr, h2);
    mgemm<<<dim3(2, 128), blk, 0, stream>>>(S(cn[24]), S(h2), nullptr, out, nullptr, qb, 1024, 2, 256);
}

// Round 10
// 579.925 us; speedup vs baseline: 1.2033x; 1.2033x over previous
//
#include <hip/hip_runtime.h>
#include <hip/hip_bf16.h>

// DCSA block, round 10: r8 grids (2 blocks/CU) + BK=64 (8 MFMA per barrier
// pair) + register-prefetch pipeline in mgemm/mconv: next K-step's A/B tiles
// are loaded into VGPRs right after the consume barrier, overlapping global
// latency with the current step's MFMA. Attention/LN/dwgelu unchanged.

using bf16 = __hip_bfloat16;
typedef short v8s __attribute__((ext_vector_type(8)));
typedef float v4f  __attribute__((ext_vector_type(4)));

static __device__ __forceinline__ float bf2f(bf16 x) { return __bfloat162float(x); }
static __device__ __forceinline__ float us2f(unsigned short u)
{ union { unsigned int i; float f; } x; x.i = ((unsigned)u) << 16; return x.f; }
static __device__ __forceinline__ unsigned short f2us(float f)
{ bf16 h = __float2bfloat16(f); return *(unsigned short*)&h; }
static __device__ __forceinline__ float ldi(const void* p, size_t i, int isbf)
{ return isbf ? bf2f(((const bf16*)p)[i]) : ((const float*)p)[i]; }

// ---------------------------------------------------------------------------
__global__ void detect_kernel(const unsigned short* p, int* flag)
{
    if (threadIdx.x == 0 && blockIdx.x == 0)
        *flag = (p[0] == 0x3F80) ? 1 : 0;
}

// ---------------------------------------------------------------------------
struct CvtArgs { const void* src[20]; unsigned off[21]; };

__global__ __launch_bounds__(256) void cvt_lin(CvtArgs a, const int* __restrict__ flag,
                                               bf16* __restrict__ dst)
{
    unsigned e = blockIdx.x * 256u + threadIdx.x;
    int isbf = *flag;
    int s = 0;
    while (e >= a.off[s + 1]) ++s;
    dst[e] = __float2bfloat16(ldi(a.src[s], e - a.off[s], isbf));
}

// ---------------------------------------------------------------------------
__global__ __launch_bounds__(256) void tcvt(const void* __restrict__ src,
                                            const int* __restrict__ flag,
                                            bf16* __restrict__ dst)
{
    __shared__ float T[64][65];
    int hw0 = blockIdx.x * 64, c0 = blockIdx.y * 64, b = blockIdx.z;
    int t = threadIdx.x, isbf = *flag;
    int c = t >> 2, x16 = (t & 3) * 16;
    size_t sbase = ((size_t)b * 256 + c0 + c) * 1024 + hw0 + x16;
#pragma unroll
    for (int j = 0; j < 16; ++j) T[c][x16 + j] = ldi(src, sbase + j, isbf);
    __syncthreads();
    int hw = t >> 2, c16 = (t & 3) * 16;
    bf16* dp = dst + ((size_t)(b << 10) + hw0 + hw) * 256 + c0 + c16;
#pragma unroll
    for (int j = 0; j < 16; ++j) dp[j] = __float2bfloat16(T[c16 + j][hw]);
}

// ---------------------------------------------------------------------------
template <int KS>
__global__ __launch_bounds__(256) void repack_conv(const void* __restrict__ W,
                                                   const int* __restrict__ flag,
                                                   bf16* __restrict__ Wr)
{
    int idx = blockIdx.x * 256 + threadIdx.x;
    int isbf = *flag;
    int ci = idx & 255, o = (idx >> 8) & 255, khkw = idx >> 16;
    int kh = khkw / KS, kw = khkw % KS;
    Wr[idx] = __float2bfloat16(
        ldi(W, (((size_t)o * 256 + ci) * KS + kh) * KS + kw, isbf));
}

__global__ __launch_bounds__(256) void repack_dw(const void* __restrict__ W,
                                                 const int* __restrict__ flag,
                                                 bf16* __restrict__ Wr)
{
    int idx = blockIdx.x * 256 + threadIdx.x;
    int isbf = *flag;
    int c = idx & 1023, tap = idx >> 10;
    Wr[idx] = __float2bfloat16(ldi(W, (size_t)c * 9 + tap, isbf));
}

// ---------------------------------------------------------------------------
// MFMA GEMM, 64x64 tile, BK=64, 4 waves (each 16m x 64n, 8 MFMA/barrier-pair),
// register-prefetch pipeline. MA:[M][K], MB:[N][K] k-contig.
// modes: 0 NHWC(+R) / 1 CHW / 2 CHW-fp32+R / 3 qkv-split / 4 QK col-offset
// ---------------------------------------------------------------------------
__global__ __launch_bounds__(256) void mgemm(
    const short* __restrict__ MA, const short* __restrict__ MB,
    bf16* __restrict__ Yb, float* __restrict__ Yf, bf16* __restrict__ Y2,
    const bf16* __restrict__ R, int K, int mode, int Ochan)
{
    __shared__ short As[64][72], Bs[64][72];
    int m0 = blockIdx.x * 64, n0 = blockIdx.y * 64;
    int t = threadIdx.x, lane = t & 63, wv = t >> 6;
    int l15 = lane & 15, quad = lane >> 4;
    int srow = t >> 2, scol = (t & 3) * 16;

    const short* pa = &MA[(size_t)(m0 + srow) * K + scol];
    const short* pb = &MB[(size_t)(n0 + srow) * K + scol];

    v4f acc[4] = {};
    v8s ra0 = *(const v8s*)&pa[0], ra1 = *(const v8s*)&pa[8];
    v8s rb0 = *(const v8s*)&pb[0], rb1 = *(const v8s*)&pb[8];

    for (int k0 = 0; k0 < K; k0 += 64) {
        if (k0) __syncthreads();
        *(v8s*)&As[srow][scol]     = ra0;
        *(v8s*)&As[srow][scol + 8] = ra1;
        *(v8s*)&Bs[srow][scol]     = rb0;
        *(v8s*)&Bs[srow][scol + 8] = rb1;
        __syncthreads();
        if (k0 + 64 < K) {
            ra0 = *(const v8s*)&pa[k0 + 64];
            ra1 = *(const v8s*)&pa[k0 + 72];
            rb0 = *(const v8s*)&pb[k0 + 64];
            rb1 = *(const v8s*)&pb[k0 + 72];
        }
#pragma unroll
        for (int kk = 0; kk < 2; ++kk) {
            v8s a = *(const v8s*)&As[wv * 16 + l15][kk * 32 + quad * 8];
#pragma unroll
            for (int nt = 0; nt < 4; ++nt) {
                v8s b = *(const v8s*)&Bs[nt * 16 + l15][kk * 32 + quad * 8];
                acc[nt] = __builtin_amdgcn_mfma_f32_16x16x32_bf16(a, b, acc[nt], 0, 0, 0);
            }
        }
    }

#pragma unroll
    for (int nt = 0; nt < 4; ++nt)
#pragma unroll
        for (int r = 0; r < 4; ++r) {
            int mm = m0 + wv * 16 + quad * 4 + r;
            int nn = n0 + nt * 16 + l15;
            float v = acc[nt][r];
            if (mode == 0) {
                size_t off = (size_t)mm * Ochan + nn;
                if (R) v += bf2f(R[off]);
                Yb[off] = __float2bfloat16(v);
            } else if (mode == 1) {
                Yb[((size_t)(nn >> 10) * Ochan + mm) * 1024 + (nn & 1023)] =
                    __float2bfloat16(v);
            } else if (mode == 2) {
                Yf[((size_t)(nn >> 10) * Ochan + mm) * 1024 + (nn & 1023)] =
                    v + bf2f(R[(size_t)nn * 256 + mm]);
            } else if (mode == 3) {
                if (mm < 512) Yb[(size_t)nn * 512 + mm] = __float2bfloat16(v);
                else Y2[((size_t)(nn >> 10) * 256 + (mm - 512)) * 1024 + (nn & 1023)] =
                         __float2bfloat16(v);
            } else {
                Yb[(size_t)nn * 512 + Ochan + mm] = __float2bfloat16(v);
            }
        }
}

// ---------------------------------------------------------------------------
// MFMA conv, same 64x64 / BK=64 prefetch skeleton, im2col A staging.
// grid (128, 4).
// ---------------------------------------------------------------------------
template <int KS, int PAD>
__global__ __launch_bounds__(256) void mconv(
    const short* __restrict__ Xn, const short* __restrict__ Wr,
    bf16* __restrict__ Y)
{
    const int K = 256 * KS * KS;
    __shared__ short As[64][72], Bs[64][72];
    int p0 = blockIdx.x * 64, o0 = blockIdx.y * 64;
    int t = threadIdx.x, lane = t & 63, wv = t >> 6;
    int l15 = lane & 15, quad = lane >> 4;
    int srow = t >> 2, scol = (t & 3) * 16;

    int p  = p0 + srow;
    int hw = p & 1023, hh = hw >> 5, ww = hw & 31;
    size_t ib = ((size_t)(p >> 10)) << 10;

    v4f acc[4] = {};
    v8s ra0, ra1, rb0, rb1;

    // load for k0
    {
        int kh0 = 0 / KS, kw0 = 0 % KS;
        int hi = hh + kh0 - PAD, wi = ww + kw0 - PAD;
        v8s z = {0, 0, 0, 0, 0, 0, 0, 0};
        ra0 = z; ra1 = z;
        if ((unsigned)hi < 32u && (unsigned)wi < 32u) {
            const short* sa = &Xn[(ib + (hi << 5) + wi) * 256 + scol];
            ra0 = *(const v8s*)&sa[0];
            ra1 = *(const v8s*)&sa[8];
        }
        const short* sb = &Wr[((size_t)0 * 256 + o0 + srow) * 256 + scol];
        rb0 = *(const v8s*)&sb[0];
        rb1 = *(const v8s*)&sb[8];
    }

    for (int k0 = 0; k0 < K; k0 += 64) {
        if (k0) __syncthreads();
        *(v8s*)&As[srow][scol]     = ra0;
        *(v8s*)&As[srow][scol + 8] = ra1;
        *(v8s*)&Bs[srow][scol]     = rb0;
        *(v8s*)&Bs[srow][scol + 8] = rb1;
        __syncthreads();
        int kn = k0 + 64;
        if (kn < K) {
            int khkw = kn >> 8;
            int kh = khkw / KS, kw = khkw % KS;
            int hi = hh + kh - PAD, wi = ww + kw - PAD;
            int aci = (kn & 255) + scol;
            v8s z = {0, 0, 0, 0, 0, 0, 0, 0};
            ra0 = z; ra1 = z;
            if ((unsigned)hi < 32u && (unsigned)wi < 32u) {
                const short* sa = &Xn[(ib + (hi << 5) + wi) * 256 + aci];
                ra0 = *(const v8s*)&sa[0];
                ra1 = *(const v8s*)&sa[8];
            }
            const short* sb = &Wr[((size_t)khkw * 256 + o0 + srow) * 256 + (kn & 255) + scol];
            rb0 = *(const v8s*)&sb[0];
            rb1 = *(const v8s*)&sb[8];
        }
#pragma unroll
        for (int kk = 0; kk < 2; ++kk) {
            v8s a = *(const v8s*)&As[wv * 16 + l15][kk * 32 + quad * 8];
#pragma unroll
            for (int nt = 0; nt < 4; ++nt) {
                v8s b = *(const v8s*)&Bs[nt * 16 + l15][kk * 32 + quad * 8];
                acc[nt] = __builtin_amdgcn_mfma_f32_16x16x32_bf16(a, b, acc[nt], 0, 0, 0);
            }
        }
    }

#pragma unroll
    for (int nt = 0; nt < 4; ++nt)
#pragma unroll
        for (int r = 0; r < 4; ++r) {
            int pp = p0 + wv * 16 + quad * 4 + r;
            int oo = o0 + nt * 16 + l15;
            Y[(size_t)pp * 256 + oo] = __float2bfloat16(acc[nt][r]);
        }
}

// ---------------------------------------------------------------------------
// MFMA flash attention (unchanged, verified).
// ---------------------------------------------------------------------------
__global__ __launch_bounds__(256) void attn_mfma(
    const bf16* __restrict__ QK, const bf16* __restrict__ V,
    bf16* __restrict__ Out)
{
    int b = blockIdx.z, h = blockIdx.y, n0 = blockIdx.x * 64;
    int t = threadIdx.x, lane = t & 63, wv = t >> 6;
    int l15 = lane & 15, quad = lane >> 4;

    __shared__ short Ps[4][16][72];

    const short* qk = (const short*)QK;
    const short* vp = (const short*)V + ((size_t)b * 256 + h * 64) * 1024;

    size_t qrow = ((size_t)b * 1024 + n0 + wv * 16 + l15) * 512 + h * 64;
    v8s qf0 = *(const v8s*)&qk[qrow + quad * 8];
    v8s qf1 = *(const v8s*)&qk[qrow + 32 + quad * 8];

    v4f oacc[4] = {};
    float mi[4], li[4];
#pragma unroll
    for (int r = 0; r < 4; ++r) { mi[r] = -1e30f; li[r] = 0.f; }
    const float LOG2E = 1.4426950408889634f;

    for (int m0 = 0; m0 < 1024; m0 += 64) {
        v4f sacc[4];
#pragma unroll
        for (int ct = 0; ct < 4; ++ct) {
            size_t krow = ((size_t)b * 1024 + m0 + ct * 16 + l15) * 512 + 256 + h * 64;
            v8s kf0 = *(const v8s*)&qk[krow + quad * 8];
            v8s kf1 = *(const v8s*)&qk[krow + 32 + quad * 8];
            v4f z = {0.f, 0.f, 0.f, 0.f};
            z = __builtin_amdgcn_mfma_f32_16x16x32_bf16(qf0, kf0, z, 0, 0, 0);
            z = __builtin_amdgcn_mfma_f32_16x16x32_bf16(qf1, kf1, z, 0, 0, 0);
            sacc[ct] = z;
        }

        float rmax[4];
#pragma unroll
        for (int r = 0; r < 4; ++r)
            rmax[r] = 0.125f * fmaxf(fmaxf(sacc[0][r], sacc[1][r]),
                                     fmaxf(sacc[2][r], sacc[3][r]));
#pragma unroll
        for (int mk = 1; mk <= 8; mk <<= 1)
#pragma unroll
            for (int r = 0; r < 4; ++r)
                rmax[r] = fmaxf(rmax[r], __shfl_xor(rmax[r], mk));

        float al[4];
#pragma unroll
        for (int r = 0; r < 4; ++r) {
            float mn = fmaxf(mi[r], rmax[r]);
            al[r] = exp2f((mi[r] - mn) * LOG2E);
            mi[r] = mn;
        }

        float psum[4] = {};
#pragma unroll
        for (int ct = 0; ct < 4; ++ct)
#pragma unroll
            for (int r = 0; r < 4; ++r) {
                float pvv = exp2f((sacc[ct][r] * 0.125f - mi[r]) * LOG2E);
                psum[r] += pvv;
                Ps[wv][quad * 4 + r][ct * 16 + l15] = (short)f2us(pvv);
            }
#pragma unroll
        for (int mk = 1; mk <= 8; mk <<= 1)
#pragma unroll
            for (int r = 0; r < 4; ++r)
                psum[r] += __shfl_xor(psum[r], mk);
#pragma unroll
        for (int r = 0; r < 4; ++r) {
            li[r] = li[r] * al[r] + psum[r];
#pragma unroll
            for (int dt = 0; dt < 4; ++dt) oacc[dt][r] *= al[r];
        }

        v8s pf0 = *(const v8s*)&Ps[wv][l15][quad * 8];
        v8s pf1 = *(const v8s*)&Ps[wv][l15][32 + quad * 8];
#pragma unroll
        for (int dt = 0; dt < 4; ++dt) {
            const short* vr = vp + (size_t)(dt * 16 + l15) * 1024 + m0;
            v8s vf0 = *(const v8s*)&vr[quad * 8];
            v8s vf1 = *(const v8s*)&vr[32 + quad * 8];
            oacc[dt] = __builtin_amdgcn_mfma_f32_16x16x32_bf16(pf0, vf0, oacc[dt], 0, 0, 0);
            oacc[dt] = __builtin_amdgcn_mfma_f32_16x16x32_bf16(pf1, vf1, oacc[dt], 0, 0, 0);
        }
    }

    float linv[4];
#pragma unroll
    for (int r = 0; r < 4; ++r) linv[r] = 1.0f / li[r];
    size_t pb = (size_t)b * 1024 + n0 + wv * 16;
#pragma unroll
    for (int dt = 0; dt < 4; ++dt)
#pragma unroll
        for (int r = 0; r < 4; ++r)
            Out[(pb + quad * 4 + r) * 256 + h * 64 + dt * 16 + l15] =
                __float2bfloat16(oacc[dt][r] * linv[r]);
}

// ---------------------------------------------------------------------------
__global__ __launch_bounds__(256) void ln_nhwc(
    const bf16* __restrict__ X, const bf16* __restrict__ g,
    const bf16* __restrict__ be, bf16* __restrict__ Y)
{
    int wv = threadIdx.x >> 6, lane = threadIdx.x & 63;
    size_t p = (size_t)blockIdx.x * 4 + wv;
    const ushort4 u = *(const ushort4*)(X + p * 256 + lane * 4);
    float v0 = us2f(u.x), v1 = us2f(u.y), v2 = us2f(u.z), v3 = us2f(u.w);
    float s = v0 + v1 + v2 + v3;
    float ss = v0 * v0 + v1 * v1 + v2 * v2 + v3 * v3;
#pragma unroll
    for (int off = 32; off; off >>= 1) {
        s  += __shfl_xor(s, off);
        ss += __shfl_xor(ss, off);
    }
    float mu   = s * (1.0f / 256.0f);
    float var  = ss * (1.0f / 256.0f) - mu * mu;
    float rstd = rsqrtf(fmaxf(var, 0.0f) + 1e-5f);
    const ushort4 gu = *(const ushort4*)((const unsigned short*)g + lane * 4);
    const ushort4 bu = *(const ushort4*)((const unsigned short*)be + lane * 4);
    ushort4 o;
    o.x = f2us((v0 - mu) * rstd * us2f(gu.x) + us2f(bu.x));
    o.y = f2us((v1 - mu) * rstd * us2f(gu.y) + us2f(bu.y));
    o.z = f2us((v2 - mu) * rstd * us2f(gu.z) + us2f(bu.z));
    o.w = f2us((v3 - mu) * rstd * us2f(gu.w) + us2f(bu.w));
    *(ushort4*)(Y + p * 256 + lane * 4) = o;
}

// ---------------------------------------------------------------------------
__global__ __launch_bounds__(256) void dwgelu_nhwc(
    const bf16* __restrict__ H, const bf16* __restrict__ Wr,
    bf16* __restrict__ Y)
{
    int idx = blockIdx.x * 256 + threadIdx.x;
    int p = idx >> 7, c8 = (idx & 127) * 8;
    int hw = p & 1023, hh = hw >> 5, ww = hw & 31;
    size_t ib = ((size_t)(p >> 10)) << 10;
    float acc[8] = {};
#pragma unroll
    for (int kh = 0; kh < 3; ++kh)
#pragma unroll
        for (int kw = 0; kw < 3; ++kw) {
            int hi = hh + kh - 1, wi = ww + kw - 1;
            if ((unsigned)hi < 32u && (unsigned)wi < 32u) {
                v8s hv = *(const v8s*)((const short*)H + (ib + (hi << 5) + wi) * 1024 + c8);
                v8s wvv = *(const v8s*)((const short*)Wr + (kh * 3 + kw) * 1024 + c8);
#pragma unroll
                for (int j = 0; j < 8; ++j)
                    acc[j] = fmaf(us2f((unsigned short)wvv[j]),
                                  us2f((unsigned short)hv[j]), acc[j]);
            }
        }
    short ov[8];
#pragma unroll
    for (int j = 0; j < 8; ++j) {
        float x = acc[j];
        ov[j] = (short)f2us(0.5f * x * (1.0f + erff(x * 0.70710678118654752f)));
    }
    v8s o = {ov[0], ov[1], ov[2], ov[3], ov[4], ov[5], ov[6], ov[7]};
    *(v8s*)((short*)Y + (size_t)p * 1024 + c8) = o;
}

// ---------------------------------------------------------------------------
extern "C" void kernel_launch(void* const* d_in, const int* in_sizes, int n_in,
                              void* d_out, int out_size, void* d_ws, size_t ws_size,
                              hipStream_t stream)
{
    static const int  lidx[20] = {4,5,6,7,8,9,10,11,12,13,14,15,16,17,18,19,20,21,22,24};
    static const unsigned lsz[20] = {256,256,256,256,256,256,256,256,256,256,
                                     196608,65536,196608,65536,
                                     65536,65536,65536,65536,262144,262144};
    CvtArgs args;
    unsigned pre[21]; pre[0] = 0;
    for (int i = 0; i < 20; ++i) {
        args.src[i] = d_in[lidx[i]];
        pre[i + 1] = pre[i] + lsz[i];
    }
    for (int i = 0; i < 21; ++i) args.off[i] = pre[i];
    const unsigned ltot = pre[20];

    int*  flag  = (int*)d_ws;
    bf16* canon = (bf16*)d_ws + 128;
    bf16* cn[25];
    for (int i = 0; i < 20; ++i) cn[lidx[i]] = canon + pre[i];

    bf16* Wr3  = canon + ltot;
    bf16* Wr5  = Wr3 + 589824;
    bf16* Wdwr = Wr5 + 1638400;
    const size_t SZ = 2097152;
    bf16* slab = Wdwr + 9216;
    bf16* qb   = slab + 0 * SZ;                    // q_branch -> x (NHWC)
    bf16* kvb  = slab + 1 * SZ;
    bf16* t0   = slab + 2 * SZ;
    bf16* q    = slab + 3 * SZ;
    bf16* kv   = slab + 4 * SZ;
    bf16* QKb  = slab + 5 * SZ;                    // 2 slots: [8192][512]
    bf16* Vb   = slab + 7 * SZ;                    // 1 slot: CHW
    bf16* hb   = slab + 5 * SZ;                    // 4 slots (QKb/Vb dead)
    bf16* h2   = slab + 1 * SZ;                    // 4 slots (kvb..kv dead)
    bf16* aopT = kvb;
    bf16* dopT = t0;
    float* out = (float*)d_out;

    dim3 blk(256);
    auto S = [](const bf16* p) { return (const short*)p; };

    detect_kernel<<<1, 64, 0, stream>>>((const unsigned short*)d_in[4], flag);
    cvt_lin<<<ltot / 256, blk, 0, stream>>>(args, flag, canon);
    tcvt<<<dim3(16, 4, 8), blk, 0, stream>>>(d_in[0], flag, aopT);
    tcvt<<<dim3(16, 4, 8), blk, 0, stream>>>(d_in[1], flag, dopT);
    repack_conv<3><<<2304, blk, 0, stream>>>(d_in[2], flag, Wr3);
    repack_conv<5><<<6400, blk, 0, stream>>>(d_in[3], flag, Wr5);
    repack_dw<<<36, blk, 0, stream>>>(d_in[23], flag, Wdwr);

    // branches
    mconv<3, 1><<<dim3(128, 4), blk, 0, stream>>>(S(aopT), (const short*)Wr3, qb);
    mconv<5, 2><<<dim3(128, 4), blk, 0, stream>>>(S(dopT), (const short*)Wr5, kvb);

    // q-branch self-attention
    ln_nhwc<<<2048, blk, 0, stream>>>(qb, cn[4], cn[5], t0);
    mgemm<<<dim3(12, 128), blk, 0, stream>>>(S(cn[14]), S(t0), QKb, nullptr, Vb, nullptr, 256, 3, 0);
    attn_mfma<<<dim3(16, 4, 8), blk, 0, stream>>>(QKb, Vb, t0);
    mgemm<<<dim3(128, 4), blk, 0, stream>>>(S(t0), S(cn[15]), qb, nullptr, nullptr, qb, 256, 0, 256);
    ln_nhwc<<<2048, blk, 0, stream>>>(qb, cn[8], cn[9], q);

    // kv-branch self-attention
    ln_nhwc<<<2048, blk, 0, stream>>>(kvb, cn[6], cn[7], t0);
    mgemm<<<dim3(12, 128), blk, 0, stream>>>(S(cn[16]), S(t0), QKb, nullptr, Vb, nullptr, 256, 3, 0);
    attn_mfma<<<dim3(16, 4, 8), blk, 0, stream>>>(QKb, Vb, t0);
    mgemm<<<dim3(128, 4), blk, 0, stream>>>(S(t0), S(cn[17]), kvb, nullptr, nullptr, kvb, 256, 0, 256);
    ln_nhwc<<<2048, blk, 0, stream>>>(kvb, cn[10], cn[11], kv);

    // cross attention
    mgemm<<<dim3(4, 128), blk, 0, stream>>>(S(cn[18]), S(q),  QKb, nullptr, nullptr, nullptr, 256, 4, 0);
    mgemm<<<dim3(4, 128), blk, 0, stream>>>(S(cn[19]), S(kv), QKb, nullptr, nullptr, nullptr, 256, 4, 256);
    mgemm<<<dim3(4, 128), blk, 0, stream>>>(S(cn[20]), S(kv), Vb,  nullptr, nullptr, nullptr, 256, 1, 256);
    attn_mfma<<<dim3(16, 4, 8), blk, 0, stream>>>(QKb, Vb, t0);
    mgemm<<<dim3(128, 4), blk, 0, stream>>>(S(t0), S(cn[21]), qb, nullptr, nullptr, qb, 256, 0, 256);

    // LeFF
    ln_nhwc<<<2048, blk, 0, stream>>>(qb, cn[12], cn[13], t0);
    mgemm<<<dim3(128, 16), blk, 0, stream>>>(S(t0), S(cn[22]), hb, nullptr, nullptr, nullptr, 256, 0, 1024);
    dwgelu_nhwc<<<4096, blk, 0, stream>>>(hb, Wdwr, h2);
    mgemm<<<dim3(4, 128), blk, 0, stream>>>(S(cn[24]), S(h2), nullptr, out, nullptr, qb, 1024, 2, 256);
}